// Round 5
// baseline (278.504 us; speedup 1.0000x reference)
//
#include <hip/hip_runtime.h>

// Problem constants (static per reference): x shape (B, C, H, W) fp32
#define B   64
#define C   2048
#define H   24
#define W   12
#define S   (H * W)        // 288 spatial positions per (b, c)
#define S4  (S / 4)        // 72 float4 per channel slice
#define W4  (W / 4)        // 3 float4 per row
#define NCH 32             // channel chunks
#define CCH (C / NCH)      // 64 channels per chunk
#define RH  8              // round(0.33 * 24)

// Native clang vector type — required by __builtin_nontemporal_store
// (HIP's float4 is a struct wrapper it rejects). Lowers to dwordx4 ops.
typedef float f4 __attribute__((ext_vector_type(4)));

// ---------------------------------------------------------------------------
// Structural change (round 4/5): FULL-GRID RESIDENCY.
// 288-thread blocks = 5 hw waves -> only 6 blocks/CU fit (30/32 waves).
// The old 2048-block grid = 8 blocks/CU of work -> executes as 1.33 waves
// of execution; the 512-block tail runs the machine ~25% occupied (round-1
// counter: OccupancyPercent=42). Halving the grid to 1024 blocks (4/CU
// against 6/CU capacity) makes the ENTIRE grid co-resident: no tail, every
// phase at full width. Each block processes chunks {c, c+16} of one sample.
// ---------------------------------------------------------------------------

// ---------------------------------------------------------------------------
// Kernel 1: read-only energy pass. Block (cpair, b), 288 threads, 2 tiles.
// Thread t, iteration k accesses float4 index t + 288k within the tile's
// 4608-float4 span -> the block walks contiguous 4.6 KB spans, perfectly
// coalesced. Thread t's 4 spatial positions are fixed -> register accumulate.
// Loads batched 8-deep (compiler alone pipelines only ~4-deep).
// Side effect: x ends up resident in L3 (144 MiB < 256 MiB) for kernel 2.
// ---------------------------------------------------------------------------
__global__ __launch_bounds__(288, 4) void k_energy(const float* __restrict__ x,
                                                   float* __restrict__ part) {
    const int cpair = blockIdx.x;   // 0..15
    const int b     = blockIdx.y;   // 0..B-1
    const int t     = threadIdx.x;  // 0..287
    const int f     = t % S4;
    const int g     = t / S4;

    __shared__ f4 sm4[4][S4];   // 4.6 KB

    #pragma unroll
    for (int half = 0; half < 2; ++half) {
        const int chunk = cpair + 16 * half;
        const f4* __restrict__ x4 =
            (const f4*)x + (size_t)(b * C + chunk * CCH) * S4;

        f4 acc = {0.f, 0.f, 0.f, 0.f};
        #pragma unroll
        for (int kk = 0; kk < 2; ++kk) {
            f4 v[8];
            #pragma unroll
            for (int j = 0; j < 8; ++j) v[j] = x4[t + S * (kk * 8 + j)];
            #pragma unroll
            for (int j = 0; j < 8; ++j) acc += v[j] * v[j];
        }

        if (half) __syncthreads();   // half-0 LDS reads done before overwrite
        sm4[g][f] = acc;
        __syncthreads();

        const float* sm = (const float*)sm4;
        // thread t owns spatial position t (t < 288 == S)
        part[((size_t)b * NCH + chunk) * S + t] =
            sm[0 * S + t] + sm[1 * S + t] + sm[2 * S + t] + sm[3 * S + t];
    }
}

// ---------------------------------------------------------------------------
// Kernel 2 (fused select + masked copy). Block (cpair, b), 2 tiles of the
// SAME sample -> mask computed once, used for both tiles.
//
// Ordering: tile-A's first half (8 f4/thread) is prefetched BEFORE the mask
// phase — copy loads don't depend on the mask, so the reduce+select phase
// (32 L2 loads + 2 barriers) hides under x-load latency instead of being a
// serial prologue (whole grid starts simultaneously now).
//
// Tie semantics match stable argsort(ascending)[-RH:]: on equal values the
// larger index wins a top (dropped) slot.
//
// Copy: UNIFORM multiply-mask, no branch (round-1 lesson: branching on
// keepRow[h] is wave-divergent -> partial-wave stores break write-combining,
// ~1.8 TB/s write + 24 MB partial-line overshoot). keep is 1.0 or 0.0;
// 0*x == 0 exactly (inputs finite), 1*x is bit-exact.
// Since idx = t + 288k and 288 % 72 == 0, h = (t%72)/3 is constant per
// thread -> one LDS mask read before the stores.
// Nontemporal stores keep `out` from evicting x's L3 residency (partially;
// MALL is memory-side, some late re-reads will miss regardless).
// ---------------------------------------------------------------------------
__global__ __launch_bounds__(288, 4) void k_select_copy(const float* __restrict__ x,
                                                        const float* __restrict__ part,
                                                        float* __restrict__ out) {
    const int cpair = blockIdx.x;   // 0..15
    const int b     = blockIdx.y;
    const int t     = threadIdx.x;  // 0..287

    __shared__ float act[S];
    __shared__ float rm[H];
    __shared__ float keepRow[H];

    const size_t baseA = (size_t)(b * C + cpair * CCH) * S4;
    const size_t baseB = (size_t)(b * C + (cpair + 16) * CCH) * S4;
    const f4* __restrict__ xA = (const f4*)x + baseA;
    const f4* __restrict__ xB = (const f4*)x + baseB;
    f4* __restrict__       oA = (f4*)out + baseA;
    f4* __restrict__       oB = (f4*)out + baseB;

    // 0. prefetch tile-A first half (loads are mask-independent)
    f4 v[8];
    #pragma unroll
    for (int j = 0; j < 8; ++j) v[j] = xA[t + S * j];

    // 1. reduce the 32 chunk partials -> act[288] (coalesced across t)
    {
        const float* p = part + (size_t)b * NCH * S + t;
        float sum = 0.f;
        #pragma unroll
        for (int ch = 0; ch < NCH; ch++) sum += p[(size_t)ch * S];
        act[t] = sum;
    }
    __syncthreads();

    // 2. per-row max over width -> rm[24]
    if (t < H) {
        float m = act[t * W];
        #pragma unroll
        for (int w = 1; w < W; w++) m = fmaxf(m, act[t * W + w]);
        rm[t] = m;
    }
    __syncthreads();

    // 3. rank rows; drop the top RH (ties: larger index dropped first)
    if (t < H) {
        const float mt = rm[t];
        int cnt = 0;
        #pragma unroll
        for (int j = 0; j < H; j++) {
            float mj = rm[j];
            if (mj > mt || (mj == mt && j > t)) cnt++;
        }
        keepRow[t] = (cnt < RH) ? 0.0f : 1.0f;
    }
    __syncthreads();

    // 4. masked copy (uniform, full-wave 16B stores), 8-deep batches
    const int h = (t % S4) / W4;
    const float keep = keepRow[h];

    #pragma unroll
    for (int j = 0; j < 8; ++j)
        __builtin_nontemporal_store(v[j] * keep, &oA[t + S * j]);

    #pragma unroll
    for (int j = 0; j < 8; ++j) v[j] = xA[t + S * (8 + j)];
    #pragma unroll
    for (int j = 0; j < 8; ++j)
        __builtin_nontemporal_store(v[j] * keep, &oA[t + S * (8 + j)]);

    #pragma unroll
    for (int j = 0; j < 8; ++j) v[j] = xB[t + S * j];
    #pragma unroll
    for (int j = 0; j < 8; ++j)
        __builtin_nontemporal_store(v[j] * keep, &oB[t + S * j]);

    #pragma unroll
    for (int j = 0; j < 8; ++j) v[j] = xB[t + S * (8 + j)];
    #pragma unroll
    for (int j = 0; j < 8; ++j)
        __builtin_nontemporal_store(v[j] * keep, &oB[t + S * (8 + j)]);
}

extern "C" void kernel_launch(void* const* d_in, const int* in_sizes, int n_in,
                              void* d_out, int out_size, void* d_ws, size_t ws_size,
                              hipStream_t stream) {
    const float* x   = (const float*)d_in[0];
    float*       out = (float*)d_out;

    // ws layout: [ partials: B*NCH*S floats = 2.36 MB ]
    float* part = (float*)d_ws;

    k_energy<<<dim3(NCH / 2, B), 288, 0, stream>>>(x, part);
    k_select_copy<<<dim3(NCH / 2, B), 288, 0, stream>>>(x, part, out);
}